// Round 17
// baseline (1472.772 us; speedup 1.0000x reference)
//
#include <hip/hip_runtime.h>
#include <math.h>

#define VOCAB  32000
#define EMB    256
#define HID    512
#define MAXLEN 512
#define BATCH  128
#define NCLASS 2

#define NB  16    // blocks = batch groups (8 rows each)
#define RPB 8     // rows per block
#define KP  520   // Wl row stride (bf16 elems)
#define HP  528   // hsb row stride (bf16 elems; 8*HP banks -> 2-way only)

typedef __attribute__((ext_vector_type(8))) short bf16x8;
typedef __attribute__((ext_vector_type(4))) float f32x4;

// round-to-nearest-even fp32 -> bf16 (bit form)
__device__ __forceinline__ unsigned short f2b_bits(unsigned int u) {
    return (unsigned short)((u + 0x7fffu + ((u >> 16) & 1u)) >> 16);
}

// ---------------------------------------------------------------------------
// Kernel A: embW[v][j] = b_h[j] + sum_e emb[v][e] * W_ih[e][j]  (fp32, exact)
// (unchanged — ~70 us)
// ---------------------------------------------------------------------------
__global__ __launch_bounds__(256, 1) void embw_kernel(
    const float* __restrict__ emb, const float* __restrict__ W_ih,
    const float* __restrict__ b_h, float* __restrict__ embW)
{
    __shared__ __align__(16) float aT[EMB][64];
    __shared__ __align__(16) float wS[32][HID];

    const int t    = threadIdx.x;
    const int row0 = blockIdx.x * 64;

    {
        const int row   = t >> 2;
        const int elane = t & 3;
        for (int i = 0; i < 16; ++i) {
            const int e = elane * 4 + i * 16;
            const float4 v = *reinterpret_cast<const float4*>(
                &emb[(size_t)(row0 + row) * EMB + e]);
            aT[e + 0][row] = v.x;
            aT[e + 1][row] = v.y;
            aT[e + 2][row] = v.z;
            aT[e + 3][row] = v.w;
        }
    }

    const int rg = t >> 5;
    const int cg = t & 31;

    float acc[8][16];
    #pragma unroll
    for (int r = 0; r < 8; ++r)
        #pragma unroll
        for (int c = 0; c < 16; ++c) acc[r][c] = 0.f;

    for (int ec = 0; ec < 8; ++ec) {
        __syncthreads();
        {
            const int j4  = (t & 127) * 4;
            const int keb = (t >> 7);
            #pragma unroll
            for (int i = 0; i < 16; ++i) {
                const int ke = keb + i * 2;
                const float4 v = *reinterpret_cast<const float4*>(
                    &W_ih[(size_t)(ec * 32 + ke) * HID + j4]);
                *reinterpret_cast<float4*>(&wS[ke][j4]) = v;
            }
        }
        __syncthreads();

        for (int ke = 0; ke < 32; ++ke) {
            float a8[8];
            *(float4*)&a8[0] = *(const float4*)&aT[ec * 32 + ke][rg * 8];
            *(float4*)&a8[4] = *(const float4*)&aT[ec * 32 + ke][rg * 8 + 4];
            float w16[16];
            #pragma unroll
            for (int q = 0; q < 4; ++q)
                *(float4*)&w16[q * 4] =
                    *(const float4*)&wS[ke][cg * 16 + q * 4];
            #pragma unroll
            for (int r = 0; r < 8; ++r)
                #pragma unroll
                for (int c = 0; c < 16; ++c)
                    acc[r][c] = fmaf(a8[r], w16[c], acc[r][c]);
        }
    }

    float bh[16];
    #pragma unroll
    for (int q = 0; q < 4; ++q)
        *(float4*)&bh[q * 4] = *(const float4*)&b_h[cg * 16 + q * 4];
    #pragma unroll
    for (int r = 0; r < 8; ++r) {
        const size_t orow = (size_t)(row0 + rg * 8 + r) * HID + cg * 16;
        #pragma unroll
        for (int q = 0; q < 4; ++q) {
            float4 v;
            v.x = acc[r][q * 4 + 0] + bh[q * 4 + 0];
            v.y = acc[r][q * 4 + 1] + bh[q * 4 + 1];
            v.z = acc[r][q * 4 + 2] + bh[q * 4 + 2];
            v.w = acc[r][q * 4 + 3] + bh[q * 4 + 3];
            *reinterpret_cast<float4*>(&embW[orow + q * 4]) = v;
        }
    }
}

// ---------------------------------------------------------------------------
// Kernel B: sequential RNN — EXCHANGE-FREE decomposition.
// KEY INSIGHT (R15 post-mortem): h rows evolve independently; the agent-
//   visibility sync (~1.8us/step, the R11-R15 floor) existed only because
//   columns were split across blocks. Give each block ALL 512 columns for
//   8 batch rows -> h never leaves the CU.
// 16 blocks x 512 threads. W bf16 (512 KB/CU) split:
//   * 48 bf16x8 frags/thread = 3 N-tiles/wave (tiles w, 8+w, 16+w) = 384 KB
//     in the unified VGPR/AGPR file (512 KB/CU; R13/R14 proved frag
//     residency — MFMA reads B from AGPR per ISA §10).
//   * 1 N-tile/wave (tile 24+w, cols 384..511) in LDS Wl (133 KB, R13-
//     proven [col][KP] b128 read pattern).
//   Frag materialization FORCED: staging bounces through Wl, which the
//   next pass overwrites -> loads can't sink (aliasing) — excludes the
//   R5/R6 sink/spill failure mode by construction.
// h: bf16, double-buffered hsb[2][8][HP] in LDS (17 KB). M=16 MFMA tile
//   with 8 real rows: A reads hsb[lm&7] (lanes lm/lm+8 broadcast-share);
//   lk>=2 D-rows discarded. ONE __syncthreads per step. No atomics.
// Numerics identical to R15 (bf16 W + bf16 h into MFMA, fp32 embW + accum);
//   only MFMA summation order differs (single chain vs even/odd).
// ---------------------------------------------------------------------------
__global__ __launch_bounds__(512, 1) void rnn_kernel(
    const int* __restrict__ inputs, const float* __restrict__ embW,
    const float* __restrict__ W_hh, float* __restrict__ h_final)
{
    __shared__ __align__(16) unsigned short Wl[128][KP];     // 133,120 B
    __shared__ __align__(16) unsigned short hsb[2][RPB][HP]; //  16,896 B

    const int t  = threadIdx.x;
    const int w  = t >> 6;           // wave 0..7
    const int l  = t & 63;
    const int lm = l & 15;           // MFMA row/col lane index
    const int lk = l >> 4;           // MFMA k-group / D row group
    const int ko = lk * 8;
    const int r0 = blockIdx.x * RPB;

    // ---- setup: 4 passes stage W cols [p*128, p*128+128) into Wl; the
    //      first 3 are pulled into register frags, the 4th stays in LDS ----
    bf16x8 Bf[3][16];
    #pragma unroll
    for (int p = 0; p < 4; ++p) {
        if (p > 0) __syncthreads();   // protect Wl against previous readers
        {
            const int c  = t & 127;   // local col
            const int kq = t >> 7;    // k quarter
            for (int i = 0; i < 128; i += 4) {
                const int k = kq * 128 + i;
                unsigned int u0 = __builtin_bit_cast(unsigned int,
                                    W_hh[(size_t)(k + 0) * HID + p * 128 + c]);
                unsigned int u1 = __builtin_bit_cast(unsigned int,
                                    W_hh[(size_t)(k + 1) * HID + p * 128 + c]);
                unsigned int u2 = __builtin_bit_cast(unsigned int,
                                    W_hh[(size_t)(k + 2) * HID + p * 128 + c]);
                unsigned int u3 = __builtin_bit_cast(unsigned int,
                                    W_hh[(size_t)(k + 3) * HID + p * 128 + c]);
                unsigned int p0 = (unsigned int)f2b_bits(u0) |
                                  ((unsigned int)f2b_bits(u1) << 16);
                unsigned int p1 = (unsigned int)f2b_bits(u2) |
                                  ((unsigned int)f2b_bits(u3) << 16);
                *(unsigned long long*)&Wl[c][k] =
                    (unsigned long long)p0 | ((unsigned long long)p1 << 32);
            }
        }
        __syncthreads();
        if (p < 3) {
            #pragma unroll
            for (int kt = 0; kt < 16; ++kt)
                Bf[p][kt] = *(const bf16x8*)&Wl[w * 16 + lm][kt * 32 + ko];
        }
    }

    // ---- zero h(0) buffer (buffer 0, 8 rows x HP) ----
    for (int i = t; i < RPB * HP / 4; i += 512)
        *(unsigned long long*)&hsb[0][0][i * 4] = 0ull;
    __syncthreads();

    int cur = 0;
    for (int ts = 0; ts < MAXLEN; ++ts) {
        // ---- feedforward gather (real rows only: lk<2), issued early ----
        float ev[4][4];   // [p][i]
        if (lk < 2) {
            int tok[4];
            #pragma unroll
            for (int i = 0; i < 4; ++i)
                tok[i] = inputs[(r0 + lk * 4 + i) * MAXLEN + ts];
            #pragma unroll
            for (int p = 0; p < 4; ++p)
                #pragma unroll
                for (int i = 0; i < 4; ++i)
                    ev[p][i] = embW[(size_t)tok[i] * HID + p * 128 + w * 16 + lm];
        }

        // ---- MFMA: 16 k-tiles x 4 N-tiles (3 reg + 1 LDS); A shared ----
        f32x4 acc0 = {0.f, 0.f, 0.f, 0.f};
        f32x4 acc1 = {0.f, 0.f, 0.f, 0.f};
        f32x4 acc2 = {0.f, 0.f, 0.f, 0.f};
        f32x4 acc3 = {0.f, 0.f, 0.f, 0.f};
        const unsigned short* hrow = &hsb[cur][lm & 7][0];
        const unsigned short* wrow = &Wl[w * 16 + lm][0];
        #pragma unroll
        for (int kt = 0; kt < 16; ++kt) {
            const bf16x8 a = *(const bf16x8*)&hrow[kt * 32 + ko];
            acc0 = __builtin_amdgcn_mfma_f32_16x16x32_bf16(a, Bf[0][kt], acc0, 0, 0, 0);
            acc1 = __builtin_amdgcn_mfma_f32_16x16x32_bf16(a, Bf[1][kt], acc1, 0, 0, 0);
            acc2 = __builtin_amdgcn_mfma_f32_16x16x32_bf16(a, Bf[2][kt], acc2, 0, 0, 0);
            const bf16x8 bl = *(const bf16x8*)&wrow[kt * 32 + ko];
            acc3 = __builtin_amdgcn_mfma_f32_16x16x32_bf16(a, bl, acc3, 0, 0, 0);
        }

        // ---- tanh + write h back to LDS (real rows lk<2 only) ----
        if (lk < 2) {
            #pragma unroll
            for (int i = 0; i < 4; ++i) {
                const int row = lk * 4 + i;
                const float s0 = tanhf(acc0[i] + ev[0][i]);
                const float s1 = tanhf(acc1[i] + ev[1][i]);
                const float s2 = tanhf(acc2[i] + ev[2][i]);
                const float s3 = tanhf(acc3[i] + ev[3][i]);
                hsb[cur ^ 1][row][0 * 128 + w * 16 + lm] =
                    f2b_bits(__builtin_bit_cast(unsigned int, s0));
                hsb[cur ^ 1][row][1 * 128 + w * 16 + lm] =
                    f2b_bits(__builtin_bit_cast(unsigned int, s1));
                hsb[cur ^ 1][row][2 * 128 + w * 16 + lm] =
                    f2b_bits(__builtin_bit_cast(unsigned int, s2));
                hsb[cur ^ 1][row][3 * 128 + w * 16 + lm] =
                    f2b_bits(__builtin_bit_cast(unsigned int, s3));
                if (ts == MAXLEN - 1) {
                    const size_t rowoff = (size_t)(r0 + row) * HID;
                    h_final[rowoff + 0 * 128 + w * 16 + lm] = s0;
                    h_final[rowoff + 1 * 128 + w * 16 + lm] = s1;
                    h_final[rowoff + 2 * 128 + w * 16 + lm] = s2;
                    h_final[rowoff + 3 * 128 + w * 16 + lm] = s3;
                }
            }
        }
        __syncthreads();   // single barrier/step: writes done before reads
        cur ^= 1;
    }
}

// ---------------------------------------------------------------------------
// Kernel C: logits = h_final @ W_out + b_out, sigmoid. Tiny. (fp32 input)
// ---------------------------------------------------------------------------
__global__ void head_kernel(const float* __restrict__ h_final,
                            const float* __restrict__ W_out,
                            const float* __restrict__ b_out,
                            float* __restrict__ out)
{
    const int t = threadIdx.x;
    const int b = t >> 1, c = t & 1;
    float acc = b_out[c];
    for (int k = 0; k < HID; ++k)
        acc = fmaf(h_final[(size_t)b * HID + k], W_out[k * NCLASS + c], acc);
    out[t] = 1.f / (1.f + expf(-acc));
}

// ---------------------------------------------------------------------------
extern "C" void kernel_launch(void* const* d_in, const int* in_sizes, int n_in,
                              void* d_out, int out_size, void* d_ws,
                              size_t ws_size, hipStream_t stream)
{
    const int*   inputs = (const int*)  d_in[0];
    const float* emb    = (const float*)d_in[1];
    const float* W_ih   = (const float*)d_in[2];
    const float* W_hh   = (const float*)d_in[3];
    const float* b_h    = (const float*)d_in[4];
    const float* W_out  = (const float*)d_in[5];
    const float* b_out  = (const float*)d_in[6];
    float* out = (float*)d_out;

    // ws layout: embW 64 MB | h_final 256 KB
    float* embW    = (float*)d_ws;
    float* h_final = embW + (size_t)VOCAB * HID;

    embw_kernel<<<VOCAB / 64, 256, 0, stream>>>(emb, W_ih, b_h, embW);
    rnn_kernel<<<NB, 512, 0, stream>>>(inputs, embW, W_hh, h_final);
    head_kernel<<<1, 256, 0, stream>>>(h_final, W_out, b_out, out);
}

// Round 18
// 1216.586 us; speedup vs baseline: 1.2106x; 1.2106x over previous
//
#include <hip/hip_runtime.h>
#include <math.h>

#define VOCAB  32000
#define EMB    256
#define HID    512
#define MAXLEN 512
#define BATCH  128
#define NCLASS 2

#define NB  16    // blocks = batch groups (8 rows each)
#define RPB 8     // rows per block
#define KP  520   // Wl row stride (bf16 elems)
#define HP  528   // hsb row stride (bf16 elems; 8*HP banks -> 2-way only)

typedef __attribute__((ext_vector_type(8))) short bf16x8;
typedef __attribute__((ext_vector_type(4))) float f32x4;

// round-to-nearest-even fp32 -> bf16 (bit form)
__device__ __forceinline__ unsigned short f2b_bits(unsigned int u) {
    return (unsigned short)((u + 0x7fffu + ((u >> 16) & 1u)) >> 16);
}

// fast tanh: 1 - 2/(e^{2x}+1) via v_exp_f32 + v_rcp_f32 (~5 VALU ops vs
// ~40 for library tanhf). |err| <~ 1e-6 abs — 3 orders below the bf16
// quantum bounding h. Edges: x->+inf => rcp(inf)=0 => 1; x->-inf =>
// exp2->0 => -1; x=0 => 0 exactly. (R16 lesson: tanhf was ~1.0us/step
// of the 2.6us critical path — VALUBusy 37% local on active CUs.)
__device__ __forceinline__ float fast_tanh(float x) {
    const float t = __builtin_amdgcn_exp2f(x * 2.8853900817779268f); // 2*log2(e)
    return 1.0f - 2.0f * __builtin_amdgcn_rcpf(t + 1.0f);
}

// ---------------------------------------------------------------------------
// Kernel A: embW[v][j] = b_h[j] + sum_e emb[v][e] * W_ih[e][j]  (fp32, exact)
// (unchanged — ~70 us)
// ---------------------------------------------------------------------------
__global__ __launch_bounds__(256, 1) void embw_kernel(
    const float* __restrict__ emb, const float* __restrict__ W_ih,
    const float* __restrict__ b_h, float* __restrict__ embW)
{
    __shared__ __align__(16) float aT[EMB][64];
    __shared__ __align__(16) float wS[32][HID];

    const int t    = threadIdx.x;
    const int row0 = blockIdx.x * 64;

    {
        const int row   = t >> 2;
        const int elane = t & 3;
        for (int i = 0; i < 16; ++i) {
            const int e = elane * 4 + i * 16;
            const float4 v = *reinterpret_cast<const float4*>(
                &emb[(size_t)(row0 + row) * EMB + e]);
            aT[e + 0][row] = v.x;
            aT[e + 1][row] = v.y;
            aT[e + 2][row] = v.z;
            aT[e + 3][row] = v.w;
        }
    }

    const int rg = t >> 5;
    const int cg = t & 31;

    float acc[8][16];
    #pragma unroll
    for (int r = 0; r < 8; ++r)
        #pragma unroll
        for (int c = 0; c < 16; ++c) acc[r][c] = 0.f;

    for (int ec = 0; ec < 8; ++ec) {
        __syncthreads();
        {
            const int j4  = (t & 127) * 4;
            const int keb = (t >> 7);
            #pragma unroll
            for (int i = 0; i < 16; ++i) {
                const int ke = keb + i * 2;
                const float4 v = *reinterpret_cast<const float4*>(
                    &W_ih[(size_t)(ec * 32 + ke) * HID + j4]);
                *reinterpret_cast<float4*>(&wS[ke][j4]) = v;
            }
        }
        __syncthreads();

        for (int ke = 0; ke < 32; ++ke) {
            float a8[8];
            *(float4*)&a8[0] = *(const float4*)&aT[ec * 32 + ke][rg * 8];
            *(float4*)&a8[4] = *(const float4*)&aT[ec * 32 + ke][rg * 8 + 4];
            float w16[16];
            #pragma unroll
            for (int q = 0; q < 4; ++q)
                *(float4*)&w16[q * 4] =
                    *(const float4*)&wS[ke][cg * 16 + q * 4];
            #pragma unroll
            for (int r = 0; r < 8; ++r)
                #pragma unroll
                for (int c = 0; c < 16; ++c)
                    acc[r][c] = fmaf(a8[r], w16[c], acc[r][c]);
        }
    }

    float bh[16];
    #pragma unroll
    for (int q = 0; q < 4; ++q)
        *(float4*)&bh[q * 4] = *(const float4*)&b_h[cg * 16 + q * 4];
    #pragma unroll
    for (int r = 0; r < 8; ++r) {
        const size_t orow = (size_t)(row0 + rg * 8 + r) * HID + cg * 16;
        #pragma unroll
        for (int q = 0; q < 4; ++q) {
            float4 v;
            v.x = acc[r][q * 4 + 0] + bh[q * 4 + 0];
            v.y = acc[r][q * 4 + 1] + bh[q * 4 + 1];
            v.z = acc[r][q * 4 + 2] + bh[q * 4 + 2];
            v.w = acc[r][q * 4 + 3] + bh[q * 4 + 3];
            *reinterpret_cast<float4*>(&embW[orow + q * 4]) = v;
        }
    }
}

// ---------------------------------------------------------------------------
// Kernel B: sequential RNN — EXCHANGE-FREE (R16 structure, verbatim except
// fast_tanh). 16 blocks x 512 threads; block owns 8 batch rows x ALL 512
// cols -> h never leaves the CU. W bf16: 48 frags/thread (3 N-tiles/wave)
// + 1 N-tile/wave in LDS Wl. h double-buffered bf16 in hsb. ONE
// __syncthreads per step. No atomics, no flags, no global h traffic.
// ---------------------------------------------------------------------------
__global__ __launch_bounds__(512, 1) void rnn_kernel(
    const int* __restrict__ inputs, const float* __restrict__ embW,
    const float* __restrict__ W_hh, float* __restrict__ h_final)
{
    __shared__ __align__(16) unsigned short Wl[128][KP];     // 133,120 B
    __shared__ __align__(16) unsigned short hsb[2][RPB][HP]; //  16,896 B

    const int t  = threadIdx.x;
    const int w  = t >> 6;           // wave 0..7
    const int l  = t & 63;
    const int lm = l & 15;           // MFMA row/col lane index
    const int lk = l >> 4;           // MFMA k-group / D row group
    const int ko = lk * 8;
    const int r0 = blockIdx.x * RPB;

    // ---- setup: 4 passes stage W cols [p*128, p*128+128) into Wl; the
    //      first 3 are pulled into register frags, the 4th stays in LDS ----
    bf16x8 Bf[3][16];
    #pragma unroll
    for (int p = 0; p < 4; ++p) {
        if (p > 0) __syncthreads();   // protect Wl against previous readers
        {
            const int c  = t & 127;   // local col
            const int kq = t >> 7;    // k quarter
            for (int i = 0; i < 128; i += 4) {
                const int k = kq * 128 + i;
                unsigned int u0 = __builtin_bit_cast(unsigned int,
                                    W_hh[(size_t)(k + 0) * HID + p * 128 + c]);
                unsigned int u1 = __builtin_bit_cast(unsigned int,
                                    W_hh[(size_t)(k + 1) * HID + p * 128 + c]);
                unsigned int u2 = __builtin_bit_cast(unsigned int,
                                    W_hh[(size_t)(k + 2) * HID + p * 128 + c]);
                unsigned int u3 = __builtin_bit_cast(unsigned int,
                                    W_hh[(size_t)(k + 3) * HID + p * 128 + c]);
                unsigned int p0 = (unsigned int)f2b_bits(u0) |
                                  ((unsigned int)f2b_bits(u1) << 16);
                unsigned int p1 = (unsigned int)f2b_bits(u2) |
                                  ((unsigned int)f2b_bits(u3) << 16);
                *(unsigned long long*)&Wl[c][k] =
                    (unsigned long long)p0 | ((unsigned long long)p1 << 32);
            }
        }
        __syncthreads();
        if (p < 3) {
            #pragma unroll
            for (int kt = 0; kt < 16; ++kt)
                Bf[p][kt] = *(const bf16x8*)&Wl[w * 16 + lm][kt * 32 + ko];
        }
    }

    // ---- zero h(0) buffer (buffer 0, 8 rows x HP) ----
    for (int i = t; i < RPB * HP / 4; i += 512)
        *(unsigned long long*)&hsb[0][0][i * 4] = 0ull;
    __syncthreads();

    int cur = 0;
    for (int ts = 0; ts < MAXLEN; ++ts) {
        // ---- feedforward gather (real rows only: lk<2), issued early ----
        float ev[4][4];   // [p][i]
        if (lk < 2) {
            int tok[4];
            #pragma unroll
            for (int i = 0; i < 4; ++i)
                tok[i] = inputs[(r0 + lk * 4 + i) * MAXLEN + ts];
            #pragma unroll
            for (int p = 0; p < 4; ++p)
                #pragma unroll
                for (int i = 0; i < 4; ++i)
                    ev[p][i] = embW[(size_t)tok[i] * HID + p * 128 + w * 16 + lm];
        }

        // ---- MFMA: 16 k-tiles x 4 N-tiles (3 reg + 1 LDS); A shared ----
        f32x4 acc0 = {0.f, 0.f, 0.f, 0.f};
        f32x4 acc1 = {0.f, 0.f, 0.f, 0.f};
        f32x4 acc2 = {0.f, 0.f, 0.f, 0.f};
        f32x4 acc3 = {0.f, 0.f, 0.f, 0.f};
        const unsigned short* hrow = &hsb[cur][lm & 7][0];
        const unsigned short* wrow = &Wl[w * 16 + lm][0];
        #pragma unroll
        for (int kt = 0; kt < 16; ++kt) {
            const bf16x8 a = *(const bf16x8*)&hrow[kt * 32 + ko];
            acc0 = __builtin_amdgcn_mfma_f32_16x16x32_bf16(a, Bf[0][kt], acc0, 0, 0, 0);
            acc1 = __builtin_amdgcn_mfma_f32_16x16x32_bf16(a, Bf[1][kt], acc1, 0, 0, 0);
            acc2 = __builtin_amdgcn_mfma_f32_16x16x32_bf16(a, Bf[2][kt], acc2, 0, 0, 0);
            const bf16x8 bl = *(const bf16x8*)&wrow[kt * 32 + ko];
            acc3 = __builtin_amdgcn_mfma_f32_16x16x32_bf16(a, bl, acc3, 0, 0, 0);
        }

        // ---- fast_tanh + write h back to LDS (real rows lk<2 only) ----
        if (lk < 2) {
            #pragma unroll
            for (int i = 0; i < 4; ++i) {
                const int row = lk * 4 + i;
                const float s0 = fast_tanh(acc0[i] + ev[0][i]);
                const float s1 = fast_tanh(acc1[i] + ev[1][i]);
                const float s2 = fast_tanh(acc2[i] + ev[2][i]);
                const float s3 = fast_tanh(acc3[i] + ev[3][i]);
                hsb[cur ^ 1][row][0 * 128 + w * 16 + lm] =
                    f2b_bits(__builtin_bit_cast(unsigned int, s0));
                hsb[cur ^ 1][row][1 * 128 + w * 16 + lm] =
                    f2b_bits(__builtin_bit_cast(unsigned int, s1));
                hsb[cur ^ 1][row][2 * 128 + w * 16 + lm] =
                    f2b_bits(__builtin_bit_cast(unsigned int, s2));
                hsb[cur ^ 1][row][3 * 128 + w * 16 + lm] =
                    f2b_bits(__builtin_bit_cast(unsigned int, s3));
                if (ts == MAXLEN - 1) {
                    const size_t rowoff = (size_t)(r0 + row) * HID;
                    h_final[rowoff + 0 * 128 + w * 16 + lm] = s0;
                    h_final[rowoff + 1 * 128 + w * 16 + lm] = s1;
                    h_final[rowoff + 2 * 128 + w * 16 + lm] = s2;
                    h_final[rowoff + 3 * 128 + w * 16 + lm] = s3;
                }
            }
        }
        __syncthreads();   // single barrier/step: writes done before reads
        cur ^= 1;
    }
}

// ---------------------------------------------------------------------------
// Kernel C: logits = h_final @ W_out + b_out, sigmoid. Tiny. (fp32 input)
// ---------------------------------------------------------------------------
__global__ void head_kernel(const float* __restrict__ h_final,
                            const float* __restrict__ W_out,
                            const float* __restrict__ b_out,
                            float* __restrict__ out)
{
    const int t = threadIdx.x;
    const int b = t >> 1, c = t & 1;
    float acc = b_out[c];
    for (int k = 0; k < HID; ++k)
        acc = fmaf(h_final[(size_t)b * HID + k], W_out[k * NCLASS + c], acc);
    out[t] = 1.f / (1.f + expf(-acc));
}

// ---------------------------------------------------------------------------
extern "C" void kernel_launch(void* const* d_in, const int* in_sizes, int n_in,
                              void* d_out, int out_size, void* d_ws,
                              size_t ws_size, hipStream_t stream)
{
    const int*   inputs = (const int*)  d_in[0];
    const float* emb    = (const float*)d_in[1];
    const float* W_ih   = (const float*)d_in[2];
    const float* W_hh   = (const float*)d_in[3];
    const float* b_h    = (const float*)d_in[4];
    const float* W_out  = (const float*)d_in[5];
    const float* b_out  = (const float*)d_in[6];
    float* out = (float*)d_out;

    // ws layout: embW 64 MB | h_final 256 KB
    float* embW    = (float*)d_ws;
    float* h_final = embW + (size_t)VOCAB * HID;

    embw_kernel<<<VOCAB / 64, 256, 0, stream>>>(emb, W_ih, b_h, embW);
    rnn_kernel<<<NB, 512, 0, stream>>>(inputs, embW, W_hh, h_final);
    head_kernel<<<1, 256, 0, stream>>>(h_final, W_out, b_out, out);
}